// Round 1
// baseline (3784.539 us; speedup 1.0000x reference)
//
#include <hip/hip_runtime.h>
#include <hip/hip_bf16.h>
#include <cstdint>
#include <cstddef>

#define ALPHA 0.1f
#define K_ITERS 10

// ---------------- helper kernels ----------------

__global__ __launch_bounds__(256) void init_nodes_k(float* deg, int* cnt, int* cursor, int* flag, int N_) {
    int i = blockIdx.x * 256 + threadIdx.x;
    if (i == 0) *flag = 0;
    if (i >= N_) return;
    deg[i] = 1.0f;   // self-loop weight
    cnt[i] = 0;
    cursor[i] = 0;
}

// Detect whether edge_index buffer is int64 (values in [0,N) when read as ll) or int32.
__global__ void detect_idx_k(const void* ei, int* flag, int E_, int N_) {
    int tid = threadIdx.x;
    const long long* p = (const long long*)ei;
    int bad = 0;
    int lim = (E_ < 4096) ? E_ : 4096;
    for (int i = tid; i < lim; i += 256) {
        long long v = p[i];
        if (v < 0 || v >= (long long)N_) bad = 1;
    }
    if (bad) atomicOr(flag, 1);   // 1 => buffer is int32
}

__global__ __launch_bounds__(256) void prep_edges_k(const void* ei, const float* ew,
                                                    int* r32, int* c32, float* wbuf,
                                                    float* deg, int* cnt, const int* flag, int E_) {
    int e = blockIdx.x * 256 + threadIdx.x;
    if (e >= E_) return;
    int is32 = *flag;
    int r, c;
    if (is32) {
        const int* p = (const int*)ei;
        r = p[e]; c = p[(size_t)E_ + e];
    } else {
        const long long* p = (const long long*)ei;
        r = (int)p[e]; c = (int)p[(size_t)E_ + e];
    }
    float t = ew[e];
    float wv = (fabsf(t) > 0.0f) ? 1.0f / (1.0f + expf(-t)) : 0.0f;
    r32[e] = r; c32[e] = c; wbuf[e] = wv;
    atomicAdd(&deg[c], wv);
    atomicAdd(&cnt[c], 1);
}

__global__ __launch_bounds__(256) void node_dinv_k(const float* deg, float* dinv, int N_) {
    int i = blockIdx.x * 256 + threadIdx.x;
    if (i >= N_) return;
    float d = deg[i];
    dinv[i] = (d > 0.0f) ? rsqrtf(fmaxf(d, 1e-12f)) : 0.0f;
}

__global__ __launch_bounds__(1024) void scan_k(const int* cnt, int* rowstart, int N_) {
    __shared__ int buf[1024];
    __shared__ int carry_s;
    int tid = threadIdx.x;
    if (tid == 0) carry_s = 0;
    __syncthreads();
    for (int base = 0; base < N_; base += 1024) {
        int i = base + tid;
        int v = (i < N_) ? cnt[i] : 0;
        buf[tid] = v;
        __syncthreads();
        for (int off = 1; off < 1024; off <<= 1) {
            int t = (tid >= off) ? buf[tid - off] : 0;
            __syncthreads();
            buf[tid] += t;
            __syncthreads();
        }
        int c0 = carry_s;
        if (i < N_) rowstart[i] = c0 + buf[tid] - v;   // exclusive
        __syncthreads();
        if (tid == 1023) carry_s = c0 + buf[1023];
        __syncthreads();
    }
    if (tid == 0) rowstart[N_] = carry_s;
}

__global__ __launch_bounds__(256) void fill_csr_k(const int* r32, const int* c32, const float* wbuf,
                                                  const float* dinv, const int* rowstart, int* cursor,
                                                  int* csr_src, float* csr_norm, int E_) {
    int e = blockIdx.x * 256 + threadIdx.x;
    if (e >= E_) return;
    int r = r32[e], c = c32[e];
    int pos = rowstart[c] + atomicAdd(&cursor[c], 1);
    csr_src[pos] = r;
    csr_norm[pos] = dinv[r] * wbuf[e] * dinv[c];
}

__global__ __launch_bounds__(256) void wmask_k(const float* xw, const float* W1, float* W1p, int F_, int D_) {
    int i = blockIdx.x * 256 + threadIdx.x;
    if (i >= F_ * D_) return;
    int f = i / D_;
    float t = xw[f];
    float s = (fabsf(t) > 0.0f) ? 1.0f / (1.0f + expf(-t)) : 0.0f;
    W1p[i] = s * W1[i];
}

// ---------------- fp32 tiled GEMM: C = [relu](A @ B + bias) ----------------
// A: MxK row-major, B: KxNn row-major, bias: Nn. Block computes 64x64 tile.
template<bool RELU>
__global__ __launch_bounds__(256) void gemm_k(const float* __restrict__ A, const float* __restrict__ B,
                                              const float* __restrict__ bias, float* __restrict__ C,
                                              int M, int K, int Nn) {
    const int BM = 64, BN = 64, BK = 32;
    __shared__ float As[BK][BM + 4];
    __shared__ float Bs[BK][BN + 4];
    int tid = threadIdx.x;
    int bm = blockIdx.x, bn = blockIdx.y;
    int tm = tid % 16, tn = tid / 16;
    float acc[4][4] = {};
    int row0 = bm * BM;
    for (int k0 = 0; k0 < K; k0 += BK) {
        #pragma unroll
        for (int i = 0; i < 2; ++i) {               // A tile: 64x32 = 512 float4
            int idx = tid + i * 256;
            int c4 = (idx % (BK / 4)) * 4;
            int r  = idx / (BK / 4);
            float4 v = make_float4(0.f, 0.f, 0.f, 0.f);
            int grow = row0 + r;
            if (grow < M) v = *(const float4*)&A[(size_t)grow * K + k0 + c4];
            As[c4 + 0][r] = v.x; As[c4 + 1][r] = v.y; As[c4 + 2][r] = v.z; As[c4 + 3][r] = v.w;
        }
        #pragma unroll
        for (int i = 0; i < 2; ++i) {               // B tile: 32x64 = 512 float4
            int idx = tid + i * 256;
            int c4 = (idx % (BN / 4)) * 4;
            int r  = idx / (BN / 4);
            float4 v = *(const float4*)&B[(size_t)(k0 + r) * Nn + bn * BN + c4];
            *(float4*)&Bs[r][c4] = v;
        }
        __syncthreads();
        #pragma unroll
        for (int kk = 0; kk < BK; ++kk) {
            float a[4], b[4];
            #pragma unroll
            for (int j = 0; j < 4; ++j) a[j] = As[kk][tm * 4 + j];
            #pragma unroll
            for (int j = 0; j < 4; ++j) b[j] = Bs[kk][tn * 4 + j];
            #pragma unroll
            for (int i = 0; i < 4; ++i)
                #pragma unroll
                for (int j = 0; j < 4; ++j)
                    acc[i][j] += a[i] * b[j];
        }
        __syncthreads();
    }
    #pragma unroll
    for (int i = 0; i < 4; ++i) {
        int grow = row0 + tm * 4 + i;
        if (grow >= M) continue;
        #pragma unroll
        for (int j = 0; j < 4; ++j) {
            int gcol = bn * BN + tn * 4 + j;
            float v = acc[i][j] + bias[gcol];
            if (RELU) v = fmaxf(v, 0.0f);
            C[(size_t)grow * Nn + gcol] = v;
        }
    }
}

// ---------------- propagation: z_new = (1-a)*(D^-1/2 (A+I) D^-1/2 z) + a*z0 ----------------
// One wave per node, lane = class (C == 64).
__global__ __launch_bounds__(256) void prop_k(const float* __restrict__ z, const float* __restrict__ z0,
                                              const int* __restrict__ rowstart, const int* __restrict__ csr_src,
                                              const float* __restrict__ csr_norm, const float* __restrict__ dinv,
                                              float* __restrict__ znew, int N_) {
    int node = blockIdx.x * 4 + (threadIdx.x >> 6);
    int lane = threadIdx.x & 63;
    if (node >= N_) return;
    int s = rowstart[node], e = rowstart[node + 1];
    float d = dinv[node];
    size_t rowoff = (size_t)node * 64 + lane;
    float acc = d * d * z[rowoff];             // self-loop (w=1)
    for (int j = s; j < e; ++j) {
        int src = csr_src[j];
        float nm = csr_norm[j];
        acc += nm * z[(size_t)src * 64 + lane];
    }
    znew[rowoff] = (1.0f - ALPHA) * acc + ALPHA * z0[rowoff];
}

__global__ __launch_bounds__(256) void logsoftmax_k(const float* __restrict__ z, float* __restrict__ out, int N_) {
    int node = blockIdx.x * 4 + (threadIdx.x >> 6);
    int lane = threadIdx.x & 63;
    if (node >= N_) return;
    float v = z[(size_t)node * 64 + lane];
    float m = v;
    #pragma unroll
    for (int off = 32; off; off >>= 1) m = fmaxf(m, __shfl_xor(m, off, 64));
    float ex = expf(v - m);
    float s = ex;
    #pragma unroll
    for (int off = 32; off; off >>= 1) s += __shfl_xor(s, off, 64);
    out[(size_t)node * 64 + lane] = v - m - logf(s);
}

// ---------------- launcher ----------------

extern "C" void kernel_launch(void* const* d_in, const int* in_sizes, int n_in,
                              void* d_out, int out_size, void* d_ws, size_t ws_size,
                              hipStream_t stream) {
    const float* x   = (const float*)d_in[0];
    const void*  ei  = d_in[1];
    const float* ew  = (const float*)d_in[2];
    const float* xw  = (const float*)d_in[3];
    const float* W1  = (const float*)d_in[4];
    const float* b1  = (const float*)d_in[5];
    const float* W2  = (const float*)d_in[6];
    const float* b2  = (const float*)d_in[7];

    const int F_ = in_sizes[3];          // 512
    const int N_ = in_sizes[0] / F_;     // 100000
    const int E_ = in_sizes[2];          // 3200000
    const int D_ = in_sizes[5];          // 256
    const int C_ = in_sizes[7];          // 64 (== wave size assumption for prop/logsoftmax)

    char* base = (char*)d_ws;
    size_t off = 0;
    auto take = [&](size_t bytes) -> void* {
        void* p = base + off;
        off += (bytes + 255) & ~(size_t)255;
        return p;
    };
    int*   r32      = (int*)  take((size_t)E_ * 4);
    int*   c32      = (int*)  take((size_t)E_ * 4);
    float* wbuf     = (float*)take((size_t)E_ * 4);
    int*   csr_src  = (int*)  take((size_t)E_ * 4);
    float* csr_norm = (float*)take((size_t)E_ * 4);
    float* deg      = (float*)take((size_t)N_ * 4);
    float* dinv     = (float*)take((size_t)N_ * 4);
    int*   cnt      = (int*)  take((size_t)N_ * 4);
    int*   rowstart = (int*)  take((size_t)(N_ + 1) * 4);
    int*   cursor   = (int*)  take((size_t)N_ * 4);
    int*   flag     = (int*)  take(256);
    float* W1p      = (float*)take((size_t)F_ * D_ * 4);
    float* h        = (float*)take((size_t)N_ * D_ * 4);
    float* z0       = (float*)take((size_t)N_ * C_ * 4);
    float* za       = (float*)take((size_t)N_ * C_ * 4);
    float* zb       = (float*)d_out;     // reuse d_out as second ping-pong buffer

    (void)ws_size; (void)n_in; (void)out_size;

    int nblk = (N_ + 255) / 256;
    int eblk = (E_ + 255) / 256;

    init_nodes_k<<<nblk, 256, 0, stream>>>(deg, cnt, cursor, flag, N_);
    detect_idx_k<<<1, 256, 0, stream>>>(ei, flag, E_, N_);
    prep_edges_k<<<eblk, 256, 0, stream>>>(ei, ew, r32, c32, wbuf, deg, cnt, flag, E_);
    node_dinv_k<<<nblk, 256, 0, stream>>>(deg, dinv, N_);
    scan_k<<<1, 1024, 0, stream>>>(cnt, rowstart, N_);
    fill_csr_k<<<eblk, 256, 0, stream>>>(r32, c32, wbuf, dinv, rowstart, cursor, csr_src, csr_norm, E_);
    wmask_k<<<(F_ * D_ + 255) / 256, 256, 0, stream>>>(xw, W1, W1p, F_, D_);

    dim3 g1((N_ + 63) / 64, D_ / 64);
    gemm_k<true><<<g1, 256, 0, stream>>>(x, W1p, b1, h, N_, F_, D_);
    dim3 g2((N_ + 63) / 64, C_ / 64);
    gemm_k<false><<<g2, 256, 0, stream>>>(h, W2, b2, z0, N_, D_, C_);

    int pblk = (N_ + 3) / 4;
    for (int it = 0; it < K_ITERS; ++it) {
        const float* src = (it == 0) ? z0 : ((it & 1) ? za : zb);
        float*       dst = (it & 1) ? zb : za;
        prop_k<<<pblk, 256, 0, stream>>>(src, z0, rowstart, csr_src, csr_norm, dinv, dst, N_);
    }
    // K_ITERS=10 (even): final result is in zb == d_out
    logsoftmax_k<<<pblk, 256, 0, stream>>>(zb, (float*)d_out, N_);
}

// Round 2
// 2311.129 us; speedup vs baseline: 1.6375x; 1.6375x over previous
//
#include <hip/hip_runtime.h>
#include <hip/hip_bf16.h>
#include <cstdint>
#include <cstddef>

#define ALPHA 0.1f
#define K_ITERS 10

typedef __attribute__((ext_vector_type(8))) short bf16x8;
typedef __attribute__((ext_vector_type(4))) float f32x4;

__device__ __forceinline__ unsigned short f2bf(float f) {
    unsigned int u = __float_as_uint(f);
    u += 0x7fffu + ((u >> 16) & 1u);          // RNE
    return (unsigned short)(u >> 16);
}
__device__ __forceinline__ float bf2f(unsigned short h) {
    return __uint_as_float(((unsigned int)h) << 16);
}

// ---------------- helper kernels ----------------

__global__ __launch_bounds__(256) void init_nodes_k(float* deg, int* cnt, int* cursor, int* flag, int N_) {
    int i = blockIdx.x * 256 + threadIdx.x;
    if (i == 0) *flag = 0;
    if (i >= N_) return;
    deg[i] = 1.0f;   // self-loop weight
    cnt[i] = 0;
    cursor[i] = 0;
}

// Detect whether edge_index buffer is int64 (values in [0,N) when read as ll) or int32.
__global__ void detect_idx_k(const void* ei, int* flag, int E_, int N_) {
    int tid = threadIdx.x;
    const long long* p = (const long long*)ei;
    int bad = 0;
    int lim = (E_ < 4096) ? E_ : 4096;
    for (int i = tid; i < lim; i += 256) {
        long long v = p[i];
        if (v < 0 || v >= (long long)N_) bad = 1;
    }
    if (bad) atomicOr(flag, 1);   // 1 => buffer is int32
}

__global__ __launch_bounds__(256) void prep_edges_k(const void* ei, const float* ew,
                                                    int* r32, int* c32, float* wbuf,
                                                    float* deg, int* cnt, const int* flag, int E_) {
    int e = blockIdx.x * 256 + threadIdx.x;
    if (e >= E_) return;
    int is32 = *flag;
    int r, c;
    if (is32) {
        const int* p = (const int*)ei;
        r = p[e]; c = p[(size_t)E_ + e];
    } else {
        const long long* p = (const long long*)ei;
        r = (int)p[e]; c = (int)p[(size_t)E_ + e];
    }
    float t = ew[e];
    float wv = (fabsf(t) > 0.0f) ? 1.0f / (1.0f + expf(-t)) : 0.0f;
    r32[e] = r; c32[e] = c; wbuf[e] = wv;
    atomicAdd(&deg[c], wv);
    atomicAdd(&cnt[c], 1);
}

__global__ __launch_bounds__(256) void node_dinv_k(const float* deg, float* dinv, int N_) {
    int i = blockIdx.x * 256 + threadIdx.x;
    if (i >= N_) return;
    float d = deg[i];
    dinv[i] = (d > 0.0f) ? rsqrtf(fmaxf(d, 1e-12f)) : 0.0f;
}

// hierarchical exclusive scan of cnt -> rowstart
__global__ __launch_bounds__(256) void scan1_k(const int* cnt, int* bsum, int N_) {
    __shared__ int sm[256];
    int t = threadIdx.x, i = blockIdx.x * 256 + t;
    sm[t] = (i < N_) ? cnt[i] : 0;
    __syncthreads();
    for (int off = 128; off; off >>= 1) {
        if (t < off) sm[t] += sm[t + off];
        __syncthreads();
    }
    if (t == 0) bsum[blockIdx.x] = sm[0];
}

__global__ __launch_bounds__(1024) void scan2_k(const int* bsum, int* boff, int nb) {
    __shared__ int sm[1024];
    int t = threadIdx.x;
    int v = (t < nb) ? bsum[t] : 0;
    sm[t] = v;
    __syncthreads();
    for (int off = 1; off < 1024; off <<= 1) {
        int x = (t >= off) ? sm[t - off] : 0;
        __syncthreads();
        sm[t] += x;
        __syncthreads();
    }
    if (t < nb) boff[t] = sm[t] - v;   // exclusive
}

__global__ __launch_bounds__(256) void scan3_k(const int* cnt, const int* boff, int* rowstart, int N_) {
    __shared__ int sm[256];
    int t = threadIdx.x, i = blockIdx.x * 256 + t;
    int v = (i < N_) ? cnt[i] : 0;
    sm[t] = v;
    __syncthreads();
    for (int off = 1; off < 256; off <<= 1) {
        int x = (t >= off) ? sm[t - off] : 0;
        __syncthreads();
        sm[t] += x;
        __syncthreads();
    }
    if (i < N_)  rowstart[i]  = boff[blockIdx.x] + sm[t] - v;
    if (i == N_ - 1) rowstart[N_] = boff[blockIdx.x] + sm[t];
}

// CSR fill: packed {src, norm} per edge for one 8B load/store instead of 2x4B
__global__ __launch_bounds__(256) void fill_csr_k(const int* r32, const int* c32, const float* wbuf,
                                                  const float* dinv, const int* rowstart, int* cursor,
                                                  int2* csr, int E_) {
    int e = blockIdx.x * 256 + threadIdx.x;
    if (e >= E_) return;
    int r = r32[e], c = c32[e];
    int pos = rowstart[c] + atomicAdd(&cursor[c], 1);
    float nm = dinv[r] * wbuf[e] * dinv[c];
    csr[pos] = make_int2(r, __float_as_int(nm));
}

// W1bT[n][k] = bf16( W1[k][n] * sigmoid_mask(xw[k]) ), n<D_, k<F_
__global__ __launch_bounds__(256) void w1t_k(const float* W1, const float* xw, unsigned short* W1bT, int F_, int D_) {
    int i = blockIdx.x * 256 + threadIdx.x;
    if (i >= F_ * D_) return;
    int k = i / D_, n = i % D_;
    float t = xw[k];
    float s = (fabsf(t) > 0.0f) ? 1.0f / (1.0f + expf(-t)) : 0.0f;
    W1bT[(size_t)n * F_ + k] = f2bf(W1[i] * s);
}

// W2bT[n][k] = bf16(W2[k][n]), n<C_, k<D_
__global__ __launch_bounds__(256) void w2t_k(const float* W2, unsigned short* W2bT, int D_, int C_) {
    int i = blockIdx.x * 256 + threadIdx.x;
    if (i >= D_ * C_) return;
    int k = i / C_, n = i % C_;
    W2bT[(size_t)n * D_ + k] = f2bf(W2[i]);
}

// ---------------- MFMA GEMM: C = [relu](A @ B^T_pre + bias) ----------------
// A: [M][K] row-major (fp32 or bf16). BT: [Nn][K] bf16 (k-contiguous).
// Block tile: 128 x BN, 4 waves in 2x2, each wave 64 x BN/2 via 16x16x32 MFMA.
template<int BN, bool A_BF16, bool RELU, bool OUT_BF16>
__global__ __launch_bounds__(256) void mfma_gemm_k(const void* __restrict__ Av,
                                                   const unsigned short* __restrict__ BT,
                                                   const float* __restrict__ bias,
                                                   void* __restrict__ Cout,
                                                   int M, int K, int Nn) {
    const int BK = 32;
    __shared__ __align__(16) unsigned short Asl[4][128][8];   // [kgroup][row][8k]
    __shared__ __align__(16) unsigned short Bsl[4][BN][8];    // [kgroup][col][8k]

    int tid = threadIdx.x;
    int row0 = blockIdx.x * 128;
    int n0 = blockIdx.y * BN;

    int wid = tid >> 6, lane = tid & 63;
    int wm = wid & 1, wn = wid >> 1;           // 2x2 wave grid
    const int MT = 4;                           // 64 rows per wave
    const int NT = BN / 32;                     // 16-col tiles per wave (BN/2 cols)
    int lrow = lane & 15, kg = lane >> 4;

    f32x4 acc[MT][NT];
    #pragma unroll
    for (int i = 0; i < MT; ++i)
        #pragma unroll
        for (int j = 0; j < NT; ++j) acc[i][j] = (f32x4){0.f, 0.f, 0.f, 0.f};

    int ar = tid >> 1;                 // A stage: row handled by this thread
    int akh = (tid & 1) * 16;          // k sub-range base (16 wide)
    int agrow = row0 + ar;

    for (int k0 = 0; k0 < K; k0 += BK) {
        // ---- stage A (128 x 32) ----
        unsigned short av[16];
        if (A_BF16) {
            const unsigned short* Ab = (const unsigned short*)Av;
            if (agrow < M) {
                const bf16x8* p = (const bf16x8*)&Ab[(size_t)agrow * K + k0 + akh];
                bf16x8 v0 = p[0], v1 = p[1];
                #pragma unroll
                for (int j = 0; j < 8; ++j) { av[j] = (unsigned short)v0[j]; av[8 + j] = (unsigned short)v1[j]; }
            } else {
                #pragma unroll
                for (int j = 0; j < 16; ++j) av[j] = 0;
            }
        } else {
            const float* Af = (const float*)Av;
            if (agrow < M) {
                const float4* p = (const float4*)&Af[(size_t)agrow * K + k0 + akh];
                #pragma unroll
                for (int q = 0; q < 4; ++q) {
                    float4 v = p[q];
                    av[q * 4 + 0] = f2bf(v.x); av[q * 4 + 1] = f2bf(v.y);
                    av[q * 4 + 2] = f2bf(v.z); av[q * 4 + 3] = f2bf(v.w);
                }
            } else {
                #pragma unroll
                for (int j = 0; j < 16; ++j) av[j] = 0;
            }
        }
        #pragma unroll
        for (int h2 = 0; h2 < 2; ++h2)
            *(bf16x8*)&Asl[(akh >> 3) + h2][ar][0] = *(bf16x8*)&av[h2 * 8];

        // ---- stage B (BN x 32) from BT ----
        for (int idx = tid; idx < BN * 2; idx += 256) {
            int n = idx >> 1, kh = (idx & 1) * 16;
            const bf16x8* p = (const bf16x8*)&BT[(size_t)(n0 + n) * K + k0 + kh];
            bf16x8 v0 = p[0], v1 = p[1];
            *(bf16x8*)&Bsl[(kh >> 3) + 0][n][0] = v0;
            *(bf16x8*)&Bsl[(kh >> 3) + 1][n][0] = v1;
        }
        __syncthreads();

        // ---- fragments + MFMA ----
        bf16x8 af[MT], bfr[NT];
        #pragma unroll
        for (int i = 0; i < MT; ++i)
            af[i] = *(bf16x8*)&Asl[kg][wm * 64 + i * 16 + lrow][0];
        #pragma unroll
        for (int j = 0; j < NT; ++j)
            bfr[j] = *(bf16x8*)&Bsl[kg][wn * (BN / 2) + j * 16 + lrow][0];
        #pragma unroll
        for (int i = 0; i < MT; ++i)
            #pragma unroll
            for (int j = 0; j < NT; ++j)
                acc[i][j] = __builtin_amdgcn_mfma_f32_16x16x32_bf16(af[i], bfr[j], acc[i][j], 0, 0, 0);
        __syncthreads();
    }

    // ---- epilogue: C/D layout col=lane&15, row=(lane>>4)*4+reg ----
    #pragma unroll
    for (int i = 0; i < MT; ++i) {
        #pragma unroll
        for (int j = 0; j < NT; ++j) {
            int col = n0 + wn * (BN / 2) + j * 16 + lrow;
            float bv = bias[col];
            #pragma unroll
            for (int r = 0; r < 4; ++r) {
                int grow = row0 + wm * 64 + i * 16 + kg * 4 + r;
                if (grow < M) {
                    float v = acc[i][j][r] + bv;
                    if (RELU) v = fmaxf(v, 0.0f);
                    if (OUT_BF16) ((unsigned short*)Cout)[(size_t)grow * Nn + col] = f2bf(v);
                    else          ((float*)Cout)[(size_t)grow * Nn + col] = v;
                }
            }
        }
    }
}

// ---------------- propagation (bf16 z): one wave per node, lane = class ----------------
__global__ __launch_bounds__(256) void prop_k(const unsigned short* __restrict__ z,
                                              const unsigned short* __restrict__ z0,
                                              const int* __restrict__ rowstart,
                                              const int2* __restrict__ csr,
                                              const float* __restrict__ dinv,
                                              unsigned short* __restrict__ znew, int N_) {
    int node = blockIdx.x * 4 + (threadIdx.x >> 6);
    int lane = threadIdx.x & 63;
    if (node >= N_) return;
    int s = rowstart[node], e = rowstart[node + 1];
    float d = dinv[node];
    size_t ro = (size_t)node * 64 + lane;
    float acc = d * d * bf2f(z[ro]);            // self-loop (w=1)
    int j = s;
    for (; j + 1 < e; j += 2) {
        int2 p0 = csr[j], p1 = csr[j + 1];
        float za_ = bf2f(z[(size_t)p0.x * 64 + lane]);
        float zb_ = bf2f(z[(size_t)p1.x * 64 + lane]);
        acc += __int_as_float(p0.y) * za_ + __int_as_float(p1.y) * zb_;
    }
    if (j < e) {
        int2 p0 = csr[j];
        acc += __int_as_float(p0.y) * bf2f(z[(size_t)p0.x * 64 + lane]);
    }
    float v = (1.0f - ALPHA) * acc + ALPHA * bf2f(z0[ro]);
    znew[ro] = f2bf(v);
}

__global__ __launch_bounds__(256) void logsoftmax_k(const unsigned short* __restrict__ z,
                                                    float* __restrict__ out, int N_) {
    int node = blockIdx.x * 4 + (threadIdx.x >> 6);
    int lane = threadIdx.x & 63;
    if (node >= N_) return;
    float v = bf2f(z[(size_t)node * 64 + lane]);
    float m = v;
    #pragma unroll
    for (int off = 32; off; off >>= 1) m = fmaxf(m, __shfl_xor(m, off, 64));
    float ex = expf(v - m);
    float s = ex;
    #pragma unroll
    for (int off = 32; off; off >>= 1) s += __shfl_xor(s, off, 64);
    out[(size_t)node * 64 + lane] = v - m - logf(s);
}

// ---------------- launcher ----------------

extern "C" void kernel_launch(void* const* d_in, const int* in_sizes, int n_in,
                              void* d_out, int out_size, void* d_ws, size_t ws_size,
                              hipStream_t stream) {
    const float* x   = (const float*)d_in[0];
    const void*  ei  = d_in[1];
    const float* ew  = (const float*)d_in[2];
    const float* xw  = (const float*)d_in[3];
    const float* W1  = (const float*)d_in[4];
    const float* b1  = (const float*)d_in[5];
    const float* W2  = (const float*)d_in[6];
    const float* b2  = (const float*)d_in[7];

    const int F_ = in_sizes[3];          // 512
    const int N_ = in_sizes[0] / F_;     // 100000
    const int E_ = in_sizes[2];          // 3200000
    const int D_ = in_sizes[5];          // 256
    const int C_ = in_sizes[7];          // 64

    char* base = (char*)d_ws;
    size_t off = 0;
    auto take = [&](size_t bytes) -> void* {
        void* p = base + off;
        off += (bytes + 255) & ~(size_t)255;
        return p;
    };
    int*   r32      = (int*)  take((size_t)E_ * 4);
    int*   c32      = (int*)  take((size_t)E_ * 4);
    float* wbuf     = (float*)take((size_t)E_ * 4);
    int2*  csr      = (int2*) take((size_t)E_ * 8);
    float* deg      = (float*)take((size_t)N_ * 4);
    float* dinv     = (float*)take((size_t)N_ * 4);
    int*   cnt      = (int*)  take((size_t)N_ * 4);
    int*   rowstart = (int*)  take((size_t)(N_ + 1) * 4);
    int*   cursor   = (int*)  take((size_t)N_ * 4);
    int*   flag     = (int*)  take(256);
    int*   bsum     = (int*)  take(4096 * 4);
    int*   boff     = (int*)  take(4096 * 4);
    unsigned short* W1bT = (unsigned short*)take((size_t)F_ * D_ * 2);
    unsigned short* W2bT = (unsigned short*)take((size_t)D_ * C_ * 2);
    unsigned short* h    = (unsigned short*)take((size_t)N_ * D_ * 2);
    unsigned short* z0b  = (unsigned short*)take((size_t)N_ * C_ * 2);
    unsigned short* za   = (unsigned short*)take((size_t)N_ * C_ * 2);
    unsigned short* zb   = (unsigned short*)take((size_t)N_ * C_ * 2);

    (void)ws_size; (void)n_in; (void)out_size;

    int nblk = (N_ + 255) / 256;
    int eblk = (E_ + 255) / 256;

    init_nodes_k<<<nblk, 256, 0, stream>>>(deg, cnt, cursor, flag, N_);
    detect_idx_k<<<1, 256, 0, stream>>>(ei, flag, E_, N_);
    prep_edges_k<<<eblk, 256, 0, stream>>>(ei, ew, r32, c32, wbuf, deg, cnt, flag, E_);
    node_dinv_k<<<nblk, 256, 0, stream>>>(deg, dinv, N_);
    scan1_k<<<nblk, 256, 0, stream>>>(cnt, bsum, N_);
    scan2_k<<<1, 1024, 0, stream>>>(bsum, boff, nblk);
    scan3_k<<<nblk, 256, 0, stream>>>(cnt, boff, rowstart, N_);
    fill_csr_k<<<eblk, 256, 0, stream>>>(r32, c32, wbuf, dinv, rowstart, cursor, csr, E_);
    w1t_k<<<(F_ * D_ + 255) / 256, 256, 0, stream>>>(W1, xw, W1bT, F_, D_);
    w2t_k<<<(D_ * C_ + 255) / 256, 256, 0, stream>>>(W2, W2bT, D_, C_);

    int gx = (N_ + 127) / 128;
    // gemm1: h = relu(x @ W1p + b1), output bf16
    mfma_gemm_k<128, false, true, true><<<dim3(gx, D_ / 128), 256, 0, stream>>>(
        (const void*)x, W1bT, b1, (void*)h, N_, F_, D_);
    // gemm2: z0 = h @ W2 + b2, output bf16
    mfma_gemm_k<64, true, false, true><<<dim3(gx, C_ / 64), 256, 0, stream>>>(
        (const void*)h, W2bT, b2, (void*)z0b, N_, D_, C_);

    int pblk = (N_ + 3) / 4;
    for (int it = 0; it < K_ITERS; ++it) {
        const unsigned short* src = (it == 0) ? z0b : ((it & 1) ? za : zb);
        unsigned short*       dst = (it & 1) ? zb : za;
        prop_k<<<pblk, 256, 0, stream>>>(src, z0b, rowstart, csr, dinv, dst, N_);
    }
    // K_ITERS=10 (even): final result is in zb
    logsoftmax_k<<<pblk, 256, 0, stream>>>(zb, (float*)d_out, N_);
}

// Round 3
// 1397.473 us; speedup vs baseline: 2.7081x; 1.6538x over previous
//
#include <hip/hip_runtime.h>
#include <hip/hip_bf16.h>
#include <cstdint>
#include <cstddef>

#define ALPHA 0.1f
#define K_ITERS 10

typedef __attribute__((ext_vector_type(8))) short bf16x8;
typedef __attribute__((ext_vector_type(4))) float f32x4;

__device__ __forceinline__ unsigned short f2bf(float f) {
    unsigned int u = __float_as_uint(f);
    u += 0x7fffu + ((u >> 16) & 1u);          // RNE
    return (unsigned short)(u >> 16);
}
__device__ __forceinline__ float bf2f(unsigned short h) {
    return __uint_as_float(((unsigned int)h) << 16);
}

// ---------------- helper kernels ----------------

__global__ __launch_bounds__(256) void init_nodes_k(int* cnt, int* flag, int N_) {
    int i = blockIdx.x * 256 + threadIdx.x;
    if (i == 0) *flag = 0;
    if (i >= N_) return;
    cnt[i] = 0;
}

// Detect whether edge_index buffer is int64 (values in [0,N) when read as ll) or int32.
__global__ void detect_idx_k(const void* ei, int* flag, int E_, int N_) {
    int tid = threadIdx.x;
    const long long* p = (const long long*)ei;
    int bad = 0;
    int lim = (E_ < 4096) ? E_ : 4096;
    for (int i = tid; i < lim; i += 256) {
        long long v = p[i];
        if (v < 0 || v >= (long long)N_) bad = 1;
    }
    if (bad) atomicOr(flag, 1);   // 1 => buffer is int32
}

// decode indices, compute sigmoid-masked w, histogram ranks (1 atomic/edge)
__global__ __launch_bounds__(256) void prep_edges_k(const void* ei, const float* ew,
                                                    int* r32, int* c32, float* wbuf, int* rank,
                                                    int* cnt, const int* flag, int E_) {
    int e = blockIdx.x * 256 + threadIdx.x;
    if (e >= E_) return;
    int is32 = *flag;
    int r, c;
    if (is32) {
        const int* p = (const int*)ei;
        r = p[e]; c = p[(size_t)E_ + e];
    } else {
        const long long* p = (const long long*)ei;
        r = (int)p[e]; c = (int)p[(size_t)E_ + e];
    }
    float t = ew[e];
    float wv = (fabsf(t) > 0.0f) ? 1.0f / (1.0f + expf(-t)) : 0.0f;
    r32[e] = r; c32[e] = c; wbuf[e] = wv;
    rank[e] = atomicAdd(&cnt[c], 1);
}

// hierarchical exclusive scan of cnt -> rowstart
__global__ __launch_bounds__(256) void scan1_k(const int* cnt, int* bsum, int N_) {
    __shared__ int sm[256];
    int t = threadIdx.x, i = blockIdx.x * 256 + t;
    sm[t] = (i < N_) ? cnt[i] : 0;
    __syncthreads();
    for (int off = 128; off; off >>= 1) {
        if (t < off) sm[t] += sm[t + off];
        __syncthreads();
    }
    if (t == 0) bsum[blockIdx.x] = sm[0];
}

__global__ __launch_bounds__(1024) void scan2_k(const int* bsum, int* boff, int nb) {
    __shared__ int sm[1024];
    int t = threadIdx.x;
    int v = (t < nb) ? bsum[t] : 0;
    sm[t] = v;
    __syncthreads();
    for (int off = 1; off < 1024; off <<= 1) {
        int x = (t >= off) ? sm[t - off] : 0;
        __syncthreads();
        sm[t] += x;
        __syncthreads();
    }
    if (t < nb) boff[t] = sm[t] - v;   // exclusive
}

__global__ __launch_bounds__(256) void scan3_k(const int* cnt, const int* boff, int* rowstart, int N_) {
    __shared__ int sm[256];
    int t = threadIdx.x, i = blockIdx.x * 256 + t;
    int v = (i < N_) ? cnt[i] : 0;
    sm[t] = v;
    __syncthreads();
    for (int off = 1; off < 256; off <<= 1) {
        int x = (t >= off) ? sm[t - off] : 0;
        __syncthreads();
        sm[t] += x;
        __syncthreads();
    }
    if (i < N_)  rowstart[i]  = boff[blockIdx.x] + sm[t] - v;
    if (i == N_ - 1) rowstart[N_] = boff[blockIdx.x] + sm[t];
}

// atomic-free CSR fill: pos = rowstart[c] + rank; store {src, w}
__global__ __launch_bounds__(256) void fill_csr_k(const int* r32, const int* c32, const float* wbuf,
                                                  const int* rank, const int* rowstart,
                                                  int2* csr, int E_) {
    int e = blockIdx.x * 256 + threadIdx.x;
    if (e >= E_) return;
    int c = c32[e];
    int pos = rowstart[c] + rank[e];
    csr[pos] = make_int2(r32[e], __float_as_int(wbuf[e]));
}

// wave per node: deg = 1 + sum(w over row); dinv = rsqrt
__global__ __launch_bounds__(256) void deg_dinv_k(const int2* __restrict__ csr, const int* __restrict__ rowstart,
                                                  float* __restrict__ dinv, int N_) {
    int node = blockIdx.x * 4 + (threadIdx.x >> 6);
    int lane = threadIdx.x & 63;
    if (node >= N_) return;
    int s = rowstart[node], e = rowstart[node + 1];
    float sum = 0.0f;
    for (int j = s + lane; j < e; j += 64) sum += __int_as_float(csr[j].y);
    #pragma unroll
    for (int off = 32; off; off >>= 1) sum += __shfl_xor(sum, off, 64);
    float d = sum + 1.0f;   // self-loop
    if (lane == 0) dinv[node] = (d > 0.0f) ? rsqrtf(fmaxf(d, 1e-12f)) : 0.0f;
}

// wave per node: rewrite w -> dinv[src]*w*dinv[dst] in place
__global__ __launch_bounds__(256) void norm_k(int2* __restrict__ csr, const int* __restrict__ rowstart,
                                              const float* __restrict__ dinv, int N_) {
    int node = blockIdx.x * 4 + (threadIdx.x >> 6);
    int lane = threadIdx.x & 63;
    if (node >= N_) return;
    int s = rowstart[node], e = rowstart[node + 1];
    float dc = dinv[node];
    for (int j = s + lane; j < e; j += 64) {
        int2 p = csr[j];
        float nm = dinv[p.x] * __int_as_float(p.y) * dc;
        csr[j].y = __float_as_int(nm);
    }
}

// W1bT[n][k] = bf16( W1[k][n] * sigmoid_mask(xw[k]) ), n<D_, k<F_
__global__ __launch_bounds__(256) void w1t_k(const float* W1, const float* xw, unsigned short* W1bT, int F_, int D_) {
    int i = blockIdx.x * 256 + threadIdx.x;
    if (i >= F_ * D_) return;
    int k = i / D_, n = i % D_;
    float t = xw[k];
    float s = (fabsf(t) > 0.0f) ? 1.0f / (1.0f + expf(-t)) : 0.0f;
    W1bT[(size_t)n * F_ + k] = f2bf(W1[i] * s);
}

// W2bT[n][k] = bf16(W2[k][n]), n<C_, k<D_
__global__ __launch_bounds__(256) void w2t_k(const float* W2, unsigned short* W2bT, int D_, int C_) {
    int i = blockIdx.x * 256 + threadIdx.x;
    if (i >= D_ * C_) return;
    int k = i / C_, n = i % C_;
    W2bT[(size_t)n * D_ + k] = f2bf(W2[i]);
}

// ---------------- MFMA GEMM: C = [relu](A @ B^T_pre + bias) ----------------
// A: [M][K] row-major (fp32 or bf16). BT: [Nn][K] bf16 (k-contiguous).
// Block tile: 128 x BN, 4 waves in 2x2, each wave 64 x BN/2 via 16x16x32 MFMA.
template<int BN, bool A_BF16, bool RELU, bool OUT_BF16>
__global__ __launch_bounds__(256) void mfma_gemm_k(const void* __restrict__ Av,
                                                   const unsigned short* __restrict__ BT,
                                                   const float* __restrict__ bias,
                                                   void* __restrict__ Cout,
                                                   int M, int K, int Nn) {
    const int BK = 32;
    __shared__ __align__(16) unsigned short Asl[4][128][8];   // [kgroup][row][8k]
    __shared__ __align__(16) unsigned short Bsl[4][BN][8];    // [kgroup][col][8k]

    int tid = threadIdx.x;
    int row0 = blockIdx.x * 128;
    int n0 = blockIdx.y * BN;

    int wid = tid >> 6, lane = tid & 63;
    int wm = wid & 1, wn = wid >> 1;           // 2x2 wave grid
    const int MT = 4;                           // 64 rows per wave
    const int NT = BN / 32;                     // 16-col tiles per wave (BN/2 cols)
    int lrow = lane & 15, kg = lane >> 4;

    f32x4 acc[MT][NT];
    #pragma unroll
    for (int i = 0; i < MT; ++i)
        #pragma unroll
        for (int j = 0; j < NT; ++j) acc[i][j] = (f32x4){0.f, 0.f, 0.f, 0.f};

    int ar = tid >> 1;                 // A stage: row handled by this thread
    int akh = (tid & 1) * 16;          // k sub-range base (16 wide)
    int agrow = row0 + ar;

    for (int k0 = 0; k0 < K; k0 += BK) {
        // ---- stage A (128 x 32) ----
        unsigned short av[16];
        if (A_BF16) {
            const unsigned short* Ab = (const unsigned short*)Av;
            if (agrow < M) {
                const bf16x8* p = (const bf16x8*)&Ab[(size_t)agrow * K + k0 + akh];
                bf16x8 v0 = p[0], v1 = p[1];
                #pragma unroll
                for (int j = 0; j < 8; ++j) { av[j] = (unsigned short)v0[j]; av[8 + j] = (unsigned short)v1[j]; }
            } else {
                #pragma unroll
                for (int j = 0; j < 16; ++j) av[j] = 0;
            }
        } else {
            const float* Af = (const float*)Av;
            if (agrow < M) {
                const float4* p = (const float4*)&Af[(size_t)agrow * K + k0 + akh];
                #pragma unroll
                for (int q = 0; q < 4; ++q) {
                    float4 v = p[q];
                    av[q * 4 + 0] = f2bf(v.x); av[q * 4 + 1] = f2bf(v.y);
                    av[q * 4 + 2] = f2bf(v.z); av[q * 4 + 3] = f2bf(v.w);
                }
            } else {
                #pragma unroll
                for (int j = 0; j < 16; ++j) av[j] = 0;
            }
        }
        #pragma unroll
        for (int h2 = 0; h2 < 2; ++h2)
            *(bf16x8*)&Asl[(akh >> 3) + h2][ar][0] = *(bf16x8*)&av[h2 * 8];

        // ---- stage B (BN x 32) from BT ----
        for (int idx = tid; idx < BN * 2; idx += 256) {
            int n = idx >> 1, kh = (idx & 1) * 16;
            const bf16x8* p = (const bf16x8*)&BT[(size_t)(n0 + n) * K + k0 + kh];
            bf16x8 v0 = p[0], v1 = p[1];
            *(bf16x8*)&Bsl[(kh >> 3) + 0][n][0] = v0;
            *(bf16x8*)&Bsl[(kh >> 3) + 1][n][0] = v1;
        }
        __syncthreads();

        // ---- fragments + MFMA ----
        bf16x8 af[MT], bfr[NT];
        #pragma unroll
        for (int i = 0; i < MT; ++i)
            af[i] = *(bf16x8*)&Asl[kg][wm * 64 + i * 16 + lrow][0];
        #pragma unroll
        for (int j = 0; j < NT; ++j)
            bfr[j] = *(bf16x8*)&Bsl[kg][wn * (BN / 2) + j * 16 + lrow][0];
        #pragma unroll
        for (int i = 0; i < MT; ++i)
            #pragma unroll
            for (int j = 0; j < NT; ++j)
                acc[i][j] = __builtin_amdgcn_mfma_f32_16x16x32_bf16(af[i], bfr[j], acc[i][j], 0, 0, 0);
        __syncthreads();
    }

    // ---- epilogue: C/D layout col=lane&15, row=(lane>>4)*4+reg ----
    #pragma unroll
    for (int i = 0; i < MT; ++i) {
        #pragma unroll
        for (int j = 0; j < NT; ++j) {
            int col = n0 + wn * (BN / 2) + j * 16 + lrow;
            float bv = bias[col];
            #pragma unroll
            for (int r = 0; r < 4; ++r) {
                int grow = row0 + wm * 64 + i * 16 + kg * 4 + r;
                if (grow < M) {
                    float v = acc[i][j][r] + bv;
                    if (RELU) v = fmaxf(v, 0.0f);
                    if (OUT_BF16) ((unsigned short*)Cout)[(size_t)grow * Nn + col] = f2bf(v);
                    else          ((float*)Cout)[(size_t)grow * Nn + col] = v;
                }
            }
        }
    }
}

// ---------------- propagation (bf16 z): one wave per node, lane = class ----------------
// 8-deep gather pipeline: 8 csr entries -> 8 independent z gathers in flight -> 8 FMAs.
__global__ __launch_bounds__(256) void prop_k(const unsigned short* __restrict__ z,
                                              const unsigned short* __restrict__ z0,
                                              const int* __restrict__ rowstart,
                                              const int2* __restrict__ csr,
                                              const float* __restrict__ dinv,
                                              unsigned short* __restrict__ znew, int N_) {
    int node = blockIdx.x * 4 + (threadIdx.x >> 6);
    int lane = threadIdx.x & 63;
    if (node >= N_) return;
    int s = rowstart[node], e = rowstart[node + 1];
    float d = dinv[node];
    size_t ro = (size_t)node * 64 + lane;
    float acc = d * d * bf2f(z[ro]);            // self-loop (w=1)
    int j = s;
    for (; j + 8 <= e; j += 8) {
        int2 p[8];
        #pragma unroll
        for (int q = 0; q < 8; ++q) p[q] = csr[j + q];
        float zv[8];
        #pragma unroll
        for (int q = 0; q < 8; ++q) zv[q] = bf2f(z[(size_t)p[q].x * 64 + lane]);
        #pragma unroll
        for (int q = 0; q < 8; ++q) acc += __int_as_float(p[q].y) * zv[q];
    }
    for (; j < e; ++j) {
        int2 p0 = csr[j];
        acc += __int_as_float(p0.y) * bf2f(z[(size_t)p0.x * 64 + lane]);
    }
    float v = (1.0f - ALPHA) * acc + ALPHA * bf2f(z0[ro]);
    znew[ro] = f2bf(v);
}

__global__ __launch_bounds__(256) void logsoftmax_k(const unsigned short* __restrict__ z,
                                                    float* __restrict__ out, int N_) {
    int node = blockIdx.x * 4 + (threadIdx.x >> 6);
    int lane = threadIdx.x & 63;
    if (node >= N_) return;
    float v = bf2f(z[(size_t)node * 64 + lane]);
    float m = v;
    #pragma unroll
    for (int off = 32; off; off >>= 1) m = fmaxf(m, __shfl_xor(m, off, 64));
    float ex = expf(v - m);
    float s = ex;
    #pragma unroll
    for (int off = 32; off; off >>= 1) s += __shfl_xor(s, off, 64);
    out[(size_t)node * 64 + lane] = v - m - logf(s);
}

// ---------------- launcher ----------------

extern "C" void kernel_launch(void* const* d_in, const int* in_sizes, int n_in,
                              void* d_out, int out_size, void* d_ws, size_t ws_size,
                              hipStream_t stream) {
    const float* x   = (const float*)d_in[0];
    const void*  ei  = d_in[1];
    const float* ew  = (const float*)d_in[2];
    const float* xw  = (const float*)d_in[3];
    const float* W1  = (const float*)d_in[4];
    const float* b1  = (const float*)d_in[5];
    const float* W2  = (const float*)d_in[6];
    const float* b2  = (const float*)d_in[7];

    const int F_ = in_sizes[3];          // 512
    const int N_ = in_sizes[0] / F_;     // 100000
    const int E_ = in_sizes[2];          // 3200000
    const int D_ = in_sizes[5];          // 256
    const int C_ = in_sizes[7];          // 64

    char* base = (char*)d_ws;
    size_t off = 0;
    auto take = [&](size_t bytes) -> void* {
        void* p = base + off;
        off += (bytes + 255) & ~(size_t)255;
        return p;
    };
    int*   r32      = (int*)  take((size_t)E_ * 4);
    int*   c32      = (int*)  take((size_t)E_ * 4);
    float* wbuf     = (float*)take((size_t)E_ * 4);
    int*   rank     = (int*)  take((size_t)E_ * 4);
    int2*  csr      = (int2*) take((size_t)E_ * 8);
    float* dinv     = (float*)take((size_t)N_ * 4);
    int*   cnt      = (int*)  take((size_t)N_ * 4);
    int*   rowstart = (int*)  take((size_t)(N_ + 1) * 4);
    int*   flag     = (int*)  take(256);
    int*   bsum     = (int*)  take(4096 * 4);
    int*   boff     = (int*)  take(4096 * 4);
    unsigned short* W1bT = (unsigned short*)take((size_t)F_ * D_ * 2);
    unsigned short* W2bT = (unsigned short*)take((size_t)D_ * C_ * 2);
    unsigned short* h    = (unsigned short*)take((size_t)N_ * D_ * 2);
    unsigned short* z0b  = (unsigned short*)take((size_t)N_ * C_ * 2);
    unsigned short* za   = (unsigned short*)take((size_t)N_ * C_ * 2);
    unsigned short* zb   = (unsigned short*)take((size_t)N_ * C_ * 2);

    (void)ws_size; (void)n_in; (void)out_size;

    int nblk = (N_ + 255) / 256;
    int eblk = (E_ + 255) / 256;

    init_nodes_k<<<nblk, 256, 0, stream>>>(cnt, flag, N_);
    detect_idx_k<<<1, 256, 0, stream>>>(ei, flag, E_, N_);
    prep_edges_k<<<eblk, 256, 0, stream>>>(ei, ew, r32, c32, wbuf, rank, cnt, flag, E_);
    scan1_k<<<nblk, 256, 0, stream>>>(cnt, bsum, N_);
    scan2_k<<<1, 1024, 0, stream>>>(bsum, boff, nblk);
    scan3_k<<<nblk, 256, 0, stream>>>(cnt, boff, rowstart, N_);
    fill_csr_k<<<eblk, 256, 0, stream>>>(r32, c32, wbuf, rank, rowstart, csr, E_);
    int pblk = (N_ + 3) / 4;
    deg_dinv_k<<<pblk, 256, 0, stream>>>(csr, rowstart, dinv, N_);
    norm_k<<<pblk, 256, 0, stream>>>(csr, rowstart, dinv, N_);
    w1t_k<<<(F_ * D_ + 255) / 256, 256, 0, stream>>>(W1, xw, W1bT, F_, D_);
    w2t_k<<<(D_ * C_ + 255) / 256, 256, 0, stream>>>(W2, W2bT, D_, C_);

    int gx = (N_ + 127) / 128;
    // gemm1: h = relu(x @ W1p + b1), output bf16
    mfma_gemm_k<128, false, true, true><<<dim3(gx, D_ / 128), 256, 0, stream>>>(
        (const void*)x, W1bT, b1, (void*)h, N_, F_, D_);
    // gemm2: z0 = h @ W2 + b2, output bf16
    mfma_gemm_k<64, true, false, true><<<dim3(gx, C_ / 64), 256, 0, stream>>>(
        (const void*)h, W2bT, b2, (void*)z0b, N_, D_, C_);

    for (int it = 0; it < K_ITERS; ++it) {
        const unsigned short* src = (it == 0) ? z0b : ((it & 1) ? za : zb);
        unsigned short*       dst = (it & 1) ? zb : za;
        prop_k<<<pblk, 256, 0, stream>>>(src, z0b, rowstart, csr, dinv, dst, N_);
    }
    // K_ITERS=10 (even): final result is in zb
    logsoftmax_k<<<pblk, 256, 0, stream>>>(zb, (float*)d_out, N_);
}

// Round 4
// 1126.922 us; speedup vs baseline: 3.3583x; 1.2401x over previous
//
#include <hip/hip_runtime.h>
#include <hip/hip_bf16.h>
#include <cstdint>
#include <cstddef>

#define ALPHA 0.1f
#define K_ITERS 10

typedef __attribute__((ext_vector_type(8))) short bf16x8;
typedef __attribute__((ext_vector_type(4))) float f32x4;

__device__ __forceinline__ unsigned short f2bf(float f) {
    unsigned int u = __float_as_uint(f);
    u += 0x7fffu + ((u >> 16) & 1u);          // RNE
    return (unsigned short)(u >> 16);
}
__device__ __forceinline__ float bf2f(unsigned short h) {
    return __uint_as_float(((unsigned int)h) << 16);
}

// ---------------- helper kernels ----------------

__global__ __launch_bounds__(256) void init_nodes_k(int* cnt, int* flag, int N_) {
    int i = blockIdx.x * 256 + threadIdx.x;
    if (i == 0) *flag = 0;
    if (i >= N_) return;
    cnt[i] = 0;
}

// Detect whether edge_index buffer is int64 (values in [0,N) when read as ll) or int32.
__global__ void detect_idx_k(const void* ei, int* flag, int E_, int N_) {
    int tid = threadIdx.x;
    const long long* p = (const long long*)ei;
    int bad = 0;
    int lim = (E_ < 4096) ? E_ : 4096;
    for (int i = tid; i < lim; i += 256) {
        long long v = p[i];
        if (v < 0 || v >= (long long)N_) bad = 1;
    }
    if (bad) atomicOr(flag, 1);   // 1 => buffer is int32
}

// decode indices, compute sigmoid-masked w, histogram ranks (1 atomic/edge)
__global__ __launch_bounds__(256) void prep_edges_k(const void* ei, const float* ew,
                                                    int* r32, int* c32, float* wbuf, int* rank,
                                                    int* cnt, const int* flag, int E_) {
    int e = blockIdx.x * 256 + threadIdx.x;
    if (e >= E_) return;
    int is32 = *flag;
    int r, c;
    if (is32) {
        const int* p = (const int*)ei;
        r = p[e]; c = p[(size_t)E_ + e];
    } else {
        const long long* p = (const long long*)ei;
        r = (int)p[e]; c = (int)p[(size_t)E_ + e];
    }
    float t = ew[e];
    float wv = (fabsf(t) > 0.0f) ? 1.0f / (1.0f + expf(-t)) : 0.0f;
    r32[e] = r; c32[e] = c; wbuf[e] = wv;
    rank[e] = atomicAdd(&cnt[c], 1);
}

// hierarchical exclusive scan of cnt -> rowstart
__global__ __launch_bounds__(256) void scan1_k(const int* cnt, int* bsum, int N_) {
    __shared__ int sm[256];
    int t = threadIdx.x, i = blockIdx.x * 256 + t;
    sm[t] = (i < N_) ? cnt[i] : 0;
    __syncthreads();
    for (int off = 128; off; off >>= 1) {
        if (t < off) sm[t] += sm[t + off];
        __syncthreads();
    }
    if (t == 0) bsum[blockIdx.x] = sm[0];
}

__global__ __launch_bounds__(1024) void scan2_k(const int* bsum, int* boff, int nb) {
    __shared__ int sm[1024];
    int t = threadIdx.x;
    int v = (t < nb) ? bsum[t] : 0;
    sm[t] = v;
    __syncthreads();
    for (int off = 1; off < 1024; off <<= 1) {
        int x = (t >= off) ? sm[t - off] : 0;
        __syncthreads();
        sm[t] += x;
        __syncthreads();
    }
    if (t < nb) boff[t] = sm[t] - v;   // exclusive
}

__global__ __launch_bounds__(256) void scan3_k(const int* cnt, const int* boff, int* rowstart, int N_) {
    __shared__ int sm[256];
    int t = threadIdx.x, i = blockIdx.x * 256 + t;
    int v = (i < N_) ? cnt[i] : 0;
    sm[t] = v;
    __syncthreads();
    for (int off = 1; off < 256; off <<= 1) {
        int x = (t >= off) ? sm[t - off] : 0;
        __syncthreads();
        sm[t] += x;
        __syncthreads();
    }
    if (i < N_)  rowstart[i]  = boff[blockIdx.x] + sm[t] - v;
    if (i == N_ - 1) rowstart[N_] = boff[blockIdx.x] + sm[t];
}

// atomic-free CSR fill: pos = rowstart[c] + rank; store {src, w}
__global__ __launch_bounds__(256) void fill_csr_k(const int* r32, const int* c32, const float* wbuf,
                                                  const int* rank, const int* rowstart,
                                                  int2* csr, int E_) {
    int e = blockIdx.x * 256 + threadIdx.x;
    if (e >= E_) return;
    int c = c32[e];
    int pos = rowstart[c] + rank[e];
    csr[pos] = make_int2(r32[e], __float_as_int(wbuf[e]));
}

// 32-lane group per node: deg = 1 + sum(w over row); dinv = rsqrt
__global__ __launch_bounds__(256) void deg_dinv_k(const int2* __restrict__ csr, const int* __restrict__ rowstart,
                                                  float* __restrict__ dinv, int N_) {
    int node = blockIdx.x * 8 + (threadIdx.x >> 5);
    int l = threadIdx.x & 31;
    if (node >= N_) return;
    int s = rowstart[node], e = rowstart[node + 1];
    float sum = 0.0f;
    for (int j = s + l; j < e; j += 32) sum += __int_as_float(csr[j].y);
    #pragma unroll
    for (int off = 16; off; off >>= 1) sum += __shfl_xor(sum, off, 64);
    float d = sum + 1.0f;   // self-loop
    if (l == 0) dinv[node] = (d > 0.0f) ? rsqrtf(fmaxf(d, 1e-12f)) : 0.0f;
}

// 32-lane group per node: rewrite w -> dinv[src]*w*dinv[dst] in place
__global__ __launch_bounds__(256) void norm_k(int2* __restrict__ csr, const int* __restrict__ rowstart,
                                              const float* __restrict__ dinv, int N_) {
    int node = blockIdx.x * 8 + (threadIdx.x >> 5);
    int l = threadIdx.x & 31;
    if (node >= N_) return;
    int s = rowstart[node], e = rowstart[node + 1];
    float dc = dinv[node];
    for (int j = s + l; j < e; j += 32) {
        int2 p = csr[j];
        float nm = dinv[p.x] * __int_as_float(p.y) * dc;
        csr[j].y = __float_as_int(nm);
    }
}

// W1bT[n][k] = bf16( W1[k][n] * sigmoid_mask(xw[k]) ), n<D_, k<F_
__global__ __launch_bounds__(256) void w1t_k(const float* W1, const float* xw, unsigned short* W1bT, int F_, int D_) {
    int i = blockIdx.x * 256 + threadIdx.x;
    if (i >= F_ * D_) return;
    int k = i / D_, n = i % D_;
    float t = xw[k];
    float s = (fabsf(t) > 0.0f) ? 1.0f / (1.0f + expf(-t)) : 0.0f;
    W1bT[(size_t)n * F_ + k] = f2bf(W1[i] * s);
}

// W2bT[n][k] = bf16(W2[k][n]), n<C_, k<D_
__global__ __launch_bounds__(256) void w2t_k(const float* W2, unsigned short* W2bT, int D_, int C_) {
    int i = blockIdx.x * 256 + threadIdx.x;
    if (i >= D_ * C_) return;
    int k = i / C_, n = i % C_;
    W2bT[(size_t)n * D_ + k] = f2bf(W2[i]);
}

// ---------------- MFMA GEMM: C = [relu](A @ B^T_pre + bias) ----------------
// A: [M][K] row-major (fp32 or bf16). BT: [Nn][K] bf16 (k-contiguous).
// Block tile: 128 x BN, 4 waves in 2x2, each wave 64 x BN/2 via 16x16x32 MFMA.
template<int BN, bool A_BF16, bool RELU, bool OUT_BF16>
__global__ __launch_bounds__(256) void mfma_gemm_k(const void* __restrict__ Av,
                                                   const unsigned short* __restrict__ BT,
                                                   const float* __restrict__ bias,
                                                   void* __restrict__ Cout,
                                                   int M, int K, int Nn) {
    const int BK = 32;
    __shared__ __align__(16) unsigned short Asl[4][128][8];   // [kgroup][row][8k]
    __shared__ __align__(16) unsigned short Bsl[4][BN][8];    // [kgroup][col][8k]

    int tid = threadIdx.x;
    int row0 = blockIdx.x * 128;
    int n0 = blockIdx.y * BN;

    int wid = tid >> 6, lane = tid & 63;
    int wm = wid & 1, wn = wid >> 1;           // 2x2 wave grid
    const int MT = 4;                           // 64 rows per wave
    const int NT = BN / 32;                     // 16-col tiles per wave (BN/2 cols)
    int lrow = lane & 15, kg = lane >> 4;

    f32x4 acc[MT][NT];
    #pragma unroll
    for (int i = 0; i < MT; ++i)
        #pragma unroll
        for (int j = 0; j < NT; ++j) acc[i][j] = (f32x4){0.f, 0.f, 0.f, 0.f};

    int ar = tid >> 1;                 // A stage: row handled by this thread
    int akh = (tid & 1) * 16;          // k sub-range base (16 wide)
    int agrow = row0 + ar;

    for (int k0 = 0; k0 < K; k0 += BK) {
        // ---- stage A (128 x 32) ----
        unsigned short av[16];
        if (A_BF16) {
            const unsigned short* Ab = (const unsigned short*)Av;
            if (agrow < M) {
                const bf16x8* p = (const bf16x8*)&Ab[(size_t)agrow * K + k0 + akh];
                bf16x8 v0 = p[0], v1 = p[1];
                #pragma unroll
                for (int j = 0; j < 8; ++j) { av[j] = (unsigned short)v0[j]; av[8 + j] = (unsigned short)v1[j]; }
            } else {
                #pragma unroll
                for (int j = 0; j < 16; ++j) av[j] = 0;
            }
        } else {
            const float* Af = (const float*)Av;
            if (agrow < M) {
                const float4* p = (const float4*)&Af[(size_t)agrow * K + k0 + akh];
                #pragma unroll
                for (int q = 0; q < 4; ++q) {
                    float4 v = p[q];
                    av[q * 4 + 0] = f2bf(v.x); av[q * 4 + 1] = f2bf(v.y);
                    av[q * 4 + 2] = f2bf(v.z); av[q * 4 + 3] = f2bf(v.w);
                }
            } else {
                #pragma unroll
                for (int j = 0; j < 16; ++j) av[j] = 0;
            }
        }
        #pragma unroll
        for (int h2 = 0; h2 < 2; ++h2)
            *(bf16x8*)&Asl[(akh >> 3) + h2][ar][0] = *(bf16x8*)&av[h2 * 8];

        // ---- stage B (BN x 32) from BT ----
        for (int idx = tid; idx < BN * 2; idx += 256) {
            int n = idx >> 1, kh = (idx & 1) * 16;
            const bf16x8* p = (const bf16x8*)&BT[(size_t)(n0 + n) * K + k0 + kh];
            bf16x8 v0 = p[0], v1 = p[1];
            *(bf16x8*)&Bsl[(kh >> 3) + 0][n][0] = v0;
            *(bf16x8*)&Bsl[(kh >> 3) + 1][n][0] = v1;
        }
        __syncthreads();

        // ---- fragments + MFMA ----
        bf16x8 af[MT], bfr[NT];
        #pragma unroll
        for (int i = 0; i < MT; ++i)
            af[i] = *(bf16x8*)&Asl[kg][wm * 64 + i * 16 + lrow][0];
        #pragma unroll
        for (int j = 0; j < NT; ++j)
            bfr[j] = *(bf16x8*)&Bsl[kg][wn * (BN / 2) + j * 16 + lrow][0];
        #pragma unroll
        for (int i = 0; i < MT; ++i)
            #pragma unroll
            for (int j = 0; j < NT; ++j)
                acc[i][j] = __builtin_amdgcn_mfma_f32_16x16x32_bf16(af[i], bfr[j], acc[i][j], 0, 0, 0);
        __syncthreads();
    }

    // ---- epilogue: C/D layout col=lane&15, row=(lane>>4)*4+reg ----
    #pragma unroll
    for (int i = 0; i < MT; ++i) {
        #pragma unroll
        for (int j = 0; j < NT; ++j) {
            int col = n0 + wn * (BN / 2) + j * 16 + lrow;
            float bv = bias[col];
            #pragma unroll
            for (int r = 0; r < 4; ++r) {
                int grow = row0 + wm * 64 + i * 16 + kg * 4 + r;
                if (grow < M) {
                    float v = acc[i][j][r] + bv;
                    if (RELU) v = fmaxf(v, 0.0f);
                    if (OUT_BF16) ((unsigned short*)Cout)[(size_t)grow * Nn + col] = f2bf(v);
                    else          ((float*)Cout)[(size_t)grow * Nn + col] = v;
                }
            }
        }
    }
}

// ---------------- propagation: 16 lanes per node, 4 nodes per wave ----------------
// Lane holds 4 classes (ushort4 = 8B gathers); 8-deep pipeline -> 32 rows in
// flight per wave. CSR loads are non-temporal to keep L2 for z gathers.
// LAST: fuse alpha-blend + log_softmax, write fp32 out, skip znew.
template<bool LAST>
__global__ __launch_bounds__(256) void prop16_k(const unsigned short* __restrict__ z,
                                                const unsigned short* __restrict__ z0,
                                                const int* __restrict__ rowstart,
                                                const int2* __restrict__ csr,
                                                const float* __restrict__ dinv,
                                                unsigned short* __restrict__ znew,
                                                float* __restrict__ out, int N_) {
    int node = blockIdx.x * 16 + (threadIdx.x >> 4);
    int l = threadIdx.x & 15;
    if (node >= N_) return;
    int s = rowstart[node], e = rowstart[node + 1];
    float d = dinv[node];
    size_t ro = (size_t)node * 64 + l * 4;
    ushort4 zs = *(const ushort4*)&z[ro];
    float dd = d * d;
    float a0 = dd * bf2f(zs.x), a1 = dd * bf2f(zs.y);
    float a2 = dd * bf2f(zs.z), a3 = dd * bf2f(zs.w);
    int j = s;
    for (; j + 8 <= e; j += 8) {
        long long pv[8];
        #pragma unroll
        for (int q = 0; q < 8; ++q) pv[q] = __builtin_nontemporal_load((const long long*)&csr[j + q]);
        ushort4 g[8];
        #pragma unroll
        for (int q = 0; q < 8; ++q) g[q] = *(const ushort4*)&z[(size_t)(int)pv[q] * 64 + l * 4];
        #pragma unroll
        for (int q = 0; q < 8; ++q) {
            float w = __int_as_float((int)(pv[q] >> 32));
            a0 += w * bf2f(g[q].x); a1 += w * bf2f(g[q].y);
            a2 += w * bf2f(g[q].z); a3 += w * bf2f(g[q].w);
        }
    }
    for (; j < e; ++j) {
        long long pv = __builtin_nontemporal_load((const long long*)&csr[j]);
        ushort4 g = *(const ushort4*)&z[(size_t)(int)pv * 64 + l * 4];
        float w = __int_as_float((int)(pv >> 32));
        a0 += w * bf2f(g.x); a1 += w * bf2f(g.y); a2 += w * bf2f(g.z); a3 += w * bf2f(g.w);
    }
    ushort4 z0v = *(const ushort4*)&z0[ro];
    float v0 = (1.0f - ALPHA) * a0 + ALPHA * bf2f(z0v.x);
    float v1 = (1.0f - ALPHA) * a1 + ALPHA * bf2f(z0v.y);
    float v2 = (1.0f - ALPHA) * a2 + ALPHA * bf2f(z0v.z);
    float v3 = (1.0f - ALPHA) * a3 + ALPHA * bf2f(z0v.w);
    if (!LAST) {
        ushort4 o;
        o.x = f2bf(v0); o.y = f2bf(v1); o.z = f2bf(v2); o.w = f2bf(v3);
        *(ushort4*)&znew[ro] = o;
    } else {
        float m = fmaxf(fmaxf(v0, v1), fmaxf(v2, v3));
        #pragma unroll
        for (int off = 1; off < 16; off <<= 1) m = fmaxf(m, __shfl_xor(m, off, 64));
        float sum = expf(v0 - m) + expf(v1 - m) + expf(v2 - m) + expf(v3 - m);
        #pragma unroll
        for (int off = 1; off < 16; off <<= 1) sum += __shfl_xor(sum, off, 64);
        float lg = logf(sum);
        float4 o = make_float4(v0 - m - lg, v1 - m - lg, v2 - m - lg, v3 - m - lg);
        *(float4*)&out[ro] = o;
    }
}

// ---------------- launcher ----------------

extern "C" void kernel_launch(void* const* d_in, const int* in_sizes, int n_in,
                              void* d_out, int out_size, void* d_ws, size_t ws_size,
                              hipStream_t stream) {
    const float* x   = (const float*)d_in[0];
    const void*  ei  = d_in[1];
    const float* ew  = (const float*)d_in[2];
    const float* xw  = (const float*)d_in[3];
    const float* W1  = (const float*)d_in[4];
    const float* b1  = (const float*)d_in[5];
    const float* W2  = (const float*)d_in[6];
    const float* b2  = (const float*)d_in[7];

    const int F_ = in_sizes[3];          // 512
    const int N_ = in_sizes[0] / F_;     // 100000
    const int E_ = in_sizes[2];          // 3200000
    const int D_ = in_sizes[5];          // 256
    const int C_ = in_sizes[7];          // 64

    char* base = (char*)d_ws;
    size_t off = 0;
    auto take = [&](size_t bytes) -> void* {
        void* p = base + off;
        off += (bytes + 255) & ~(size_t)255;
        return p;
    };
    int*   r32      = (int*)  take((size_t)E_ * 4);
    int*   c32      = (int*)  take((size_t)E_ * 4);
    float* wbuf     = (float*)take((size_t)E_ * 4);
    int*   rank     = (int*)  take((size_t)E_ * 4);
    int2*  csr      = (int2*) take((size_t)E_ * 8);
    float* dinv     = (float*)take((size_t)N_ * 4);
    int*   cnt      = (int*)  take((size_t)N_ * 4);
    int*   rowstart = (int*)  take((size_t)(N_ + 1) * 4);
    int*   flag     = (int*)  take(256);
    int*   bsum     = (int*)  take(4096 * 4);
    int*   boff     = (int*)  take(4096 * 4);
    unsigned short* W1bT = (unsigned short*)take((size_t)F_ * D_ * 2);
    unsigned short* W2bT = (unsigned short*)take((size_t)D_ * C_ * 2);
    unsigned short* h    = (unsigned short*)take((size_t)N_ * D_ * 2);
    unsigned short* z0b  = (unsigned short*)take((size_t)N_ * C_ * 2);
    unsigned short* za   = (unsigned short*)take((size_t)N_ * C_ * 2);
    unsigned short* zb   = (unsigned short*)take((size_t)N_ * C_ * 2);

    (void)ws_size; (void)n_in; (void)out_size;

    int nblk = (N_ + 255) / 256;
    int eblk = (E_ + 255) / 256;

    init_nodes_k<<<nblk, 256, 0, stream>>>(cnt, flag, N_);
    detect_idx_k<<<1, 256, 0, stream>>>(ei, flag, E_, N_);
    prep_edges_k<<<eblk, 256, 0, stream>>>(ei, ew, r32, c32, wbuf, rank, cnt, flag, E_);
    scan1_k<<<nblk, 256, 0, stream>>>(cnt, bsum, N_);
    scan2_k<<<1, 1024, 0, stream>>>(bsum, boff, nblk);
    scan3_k<<<nblk, 256, 0, stream>>>(cnt, boff, rowstart, N_);
    fill_csr_k<<<eblk, 256, 0, stream>>>(r32, c32, wbuf, rank, rowstart, csr, E_);
    int gblk8 = (N_ + 7) / 8;
    deg_dinv_k<<<gblk8, 256, 0, stream>>>(csr, rowstart, dinv, N_);
    norm_k<<<gblk8, 256, 0, stream>>>(csr, rowstart, dinv, N_);
    w1t_k<<<(F_ * D_ + 255) / 256, 256, 0, stream>>>(W1, xw, W1bT, F_, D_);
    w2t_k<<<(D_ * C_ + 255) / 256, 256, 0, stream>>>(W2, W2bT, D_, C_);

    int gx = (N_ + 127) / 128;
    // gemm1: h = relu(x @ W1p + b1), output bf16
    mfma_gemm_k<128, false, true, true><<<dim3(gx, D_ / 128), 256, 0, stream>>>(
        (const void*)x, W1bT, b1, (void*)h, N_, F_, D_);
    // gemm2: z0 = h @ W2 + b2, output bf16
    mfma_gemm_k<64, true, false, true><<<dim3(gx, C_ / 64), 256, 0, stream>>>(
        (const void*)h, W2bT, b2, (void*)z0b, N_, D_, C_);

    int pblk16 = (N_ + 15) / 16;
    const unsigned short* cur = z0b;
    unsigned short* bufs[2] = { za, zb };
    for (int it = 0; it < K_ITERS - 1; ++it) {
        unsigned short* dst = bufs[it & 1];
        prop16_k<false><<<pblk16, 256, 0, stream>>>(cur, z0b, rowstart, csr, dinv, dst, nullptr, N_);
        cur = dst;
    }
    prop16_k<true><<<pblk16, 256, 0, stream>>>(cur, z0b, rowstart, csr, dinv, nullptr, (float*)d_out, N_);
}

// Round 6
// 1103.937 us; speedup vs baseline: 3.4282x; 1.0208x over previous
//
#include <hip/hip_runtime.h>
#include <hip/hip_bf16.h>
#include <cstdint>
#include <cstddef>

#define ALPHA 0.1f
#define K_ITERS 10
#define NPART 8

typedef __attribute__((ext_vector_type(8))) short bf16x8;
typedef __attribute__((ext_vector_type(4))) float f32x4;
typedef __attribute__((ext_vector_type(4))) unsigned int u32x4;

__device__ __forceinline__ unsigned short f2bf(float f) {
    unsigned int u = __float_as_uint(f);
    u += 0x7fffu + ((u >> 16) & 1u);          // RNE
    return (unsigned short)(u >> 16);
}
__device__ __forceinline__ float bf2f(unsigned short h) {
    return __uint_as_float(((unsigned int)h) << 16);
}
__device__ __forceinline__ float bflo(unsigned int u) {   // low bf16 of packed pair
    return __uint_as_float(u << 16);
}
__device__ __forceinline__ float bfhi(unsigned int u) {   // high bf16 of packed pair
    return __uint_as_float(u & 0xffff0000u);
}
__device__ __forceinline__ unsigned int pack2(float a, float b) {
    return (unsigned int)f2bf(a) | ((unsigned int)f2bf(b) << 16);
}

// ---------------- helper kernels ----------------

__global__ __launch_bounds__(256) void init_cnt_k(int* cntp, int* flag, int total) {
    int i = blockIdx.x * 256 + threadIdx.x;
    if (i == 0) *flag = 0;
    if (i < total) cntp[i] = 0;
}

// Detect whether edge_index buffer is int64 (values in [0,N) when read as ll) or int32.
__global__ void detect_idx_k(const void* ei, int* flag, int E_, int N_) {
    int tid = threadIdx.x;
    const long long* p = (const long long*)ei;
    int bad = 0;
    int lim = (E_ < 4096) ? E_ : 4096;
    for (int i = tid; i < lim; i += 256) {
        long long v = p[i];
        if (v < 0 || v >= (long long)N_) bad = 1;
    }
    if (bad) atomicOr(flag, 1);   // 1 => buffer is int32
}

// decode indices, sigmoid-masked w, partitioned histogram rank (1 atomic/edge),
// pack {r,c,w,rank} into one int4 stream
__global__ __launch_bounds__(256) void prep_edges_k(const void* ei, const float* ew,
                                                    int4* epack, int* cntp,
                                                    const int* flag, int E_, int N_) {
    int e = blockIdx.x * 256 + threadIdx.x;
    if (e >= E_) return;
    int is32 = *flag;
    int r, c;
    if (is32) {
        const int* p = (const int*)ei;
        r = p[e]; c = p[(size_t)E_ + e];
    } else {
        const long long* p = (const long long*)ei;
        r = (int)p[e]; c = (int)p[(size_t)E_ + e];
    }
    float t = ew[e];
    float wv = (fabsf(t) > 0.0f) ? 1.0f / (1.0f + expf(-t)) : 0.0f;
    int part = blockIdx.x & (NPART - 1);
    int rk = atomicAdd(&cntp[part * N_ + c], 1);
    epack[e] = make_int4(r, c, __float_as_int(wv), rk);
}

// per-node: prefix over the NPART partition counts -> pofs; total -> cnt
__global__ __launch_bounds__(256) void combine_k(const int* cntp, int* pofs, int* cnt, int N_) {
    int i = blockIdx.x * 256 + threadIdx.x;
    if (i >= N_) return;
    int s = 0;
    #pragma unroll
    for (int p = 0; p < NPART; ++p) {
        int v = cntp[p * N_ + i];
        pofs[p * N_ + i] = s;
        s += v;
    }
    cnt[i] = s;
}

// hierarchical exclusive scan of cnt -> rowstart
__global__ __launch_bounds__(256) void scan1_k(const int* cnt, int* bsum, int N_) {
    __shared__ int sm[256];
    int t = threadIdx.x, i = blockIdx.x * 256 + t;
    sm[t] = (i < N_) ? cnt[i] : 0;
    __syncthreads();
    for (int off = 128; off; off >>= 1) {
        if (t < off) sm[t] += sm[t + off];
        __syncthreads();
    }
    if (t == 0) bsum[blockIdx.x] = sm[0];
}

__global__ __launch_bounds__(1024) void scan2_k(const int* bsum, int* boff, int nb) {
    __shared__ int sm[1024];
    int t = threadIdx.x;
    int v = (t < nb) ? bsum[t] : 0;
    sm[t] = v;
    __syncthreads();
    for (int off = 1; off < 1024; off <<= 1) {
        int x = (t >= off) ? sm[t - off] : 0;
        __syncthreads();
        sm[t] += x;
        __syncthreads();
    }
    if (t < nb) boff[t] = sm[t] - v;   // exclusive
}

__global__ __launch_bounds__(256) void scan3_k(const int* cnt, const int* boff, int* rowstart, int N_) {
    __shared__ int sm[256];
    int t = threadIdx.x, i = blockIdx.x * 256 + t;
    int v = (i < N_) ? cnt[i] : 0;
    sm[t] = v;
    __syncthreads();
    for (int off = 1; off < 256; off <<= 1) {
        int x = (t >= off) ? sm[t - off] : 0;
        __syncthreads();
        sm[t] += x;
        __syncthreads();
    }
    if (i < N_)  rowstart[i]  = boff[blockIdx.x] + sm[t] - v;
    if (i == N_ - 1) rowstart[N_] = boff[blockIdx.x] + sm[t];
}

// atomic-free CSR fill: pos = rowstart[c] + pofs[part][c] + rank
__global__ __launch_bounds__(256) void fill_csr_k(const int4* epack, const int* pofs,
                                                  const int* rowstart, int2* csr, int E_, int N_) {
    int e = blockIdx.x * 256 + threadIdx.x;
    if (e >= E_) return;
    int4 v = epack[e];
    int part = (e >> 8) & (NPART - 1);
    int pos = rowstart[v.y] + pofs[part * N_ + v.y] + v.w;
    csr[pos] = make_int2(v.x, v.z);
}

// 32-lane group per node: deg = 1 + sum(w over row); dinv = rsqrt
__global__ __launch_bounds__(256) void deg_dinv_k(const int2* __restrict__ csr, const int* __restrict__ rowstart,
                                                  float* __restrict__ dinv, int N_) {
    int node = blockIdx.x * 8 + (threadIdx.x >> 5);
    int l = threadIdx.x & 31;
    if (node >= N_) return;
    int s = rowstart[node], e = rowstart[node + 1];
    float sum = 0.0f;
    for (int j = s + l; j < e; j += 32) sum += __int_as_float(csr[j].y);
    #pragma unroll
    for (int off = 16; off; off >>= 1) sum += __shfl_xor(sum, off, 64);
    float d = sum + 1.0f;   // self-loop
    if (l == 0) dinv[node] = (d > 0.0f) ? rsqrtf(fmaxf(d, 1e-12f)) : 0.0f;
}

// 32-lane group per node: rewrite w -> dinv[src]*w*dinv[dst] in place
__global__ __launch_bounds__(256) void norm_k(int2* __restrict__ csr, const int* __restrict__ rowstart,
                                              const float* __restrict__ dinv, int N_) {
    int node = blockIdx.x * 8 + (threadIdx.x >> 5);
    int l = threadIdx.x & 31;
    if (node >= N_) return;
    int s = rowstart[node], e = rowstart[node + 1];
    float dc = dinv[node];
    for (int j = s + l; j < e; j += 32) {
        int2 p = csr[j];
        float nm = dinv[p.x] * __int_as_float(p.y) * dc;
        csr[j].y = __float_as_int(nm);
    }
}

// W1bT[n][k] = bf16( W1[k][n] * sigmoid_mask(xw[k]) ), n<D_, k<F_
__global__ __launch_bounds__(256) void w1t_k(const float* W1, const float* xw, unsigned short* W1bT, int F_, int D_) {
    int i = blockIdx.x * 256 + threadIdx.x;
    if (i >= F_ * D_) return;
    int k = i / D_, n = i % D_;
    float t = xw[k];
    float s = (fabsf(t) > 0.0f) ? 1.0f / (1.0f + expf(-t)) : 0.0f;
    W1bT[(size_t)n * F_ + k] = f2bf(W1[i] * s);
}

// W2bT[n][k] = bf16(W2[k][n]), n<C_, k<D_
__global__ __launch_bounds__(256) void w2t_k(const float* W2, unsigned short* W2bT, int D_, int C_) {
    int i = blockIdx.x * 256 + threadIdx.x;
    if (i >= D_ * C_) return;
    int k = i / C_, n = i % C_;
    W2bT[(size_t)n * D_ + k] = f2bf(W2[i]);
}

// ---------------- MFMA GEMM: C = [relu](A @ B^T_pre + bias) ----------------
template<int BN, bool A_BF16, bool RELU, bool OUT_BF16>
__global__ __launch_bounds__(256) void mfma_gemm_k(const void* __restrict__ Av,
                                                   const unsigned short* __restrict__ BT,
                                                   const float* __restrict__ bias,
                                                   void* __restrict__ Cout,
                                                   int M, int K, int Nn) {
    const int BK = 32;
    __shared__ __align__(16) unsigned short Asl[4][128][8];   // [kgroup][row][8k]
    __shared__ __align__(16) unsigned short Bsl[4][BN][8];    // [kgroup][col][8k]

    int tid = threadIdx.x;
    int row0 = blockIdx.x * 128;
    int n0 = blockIdx.y * BN;

    int wid = tid >> 6, lane = tid & 63;
    int wm = wid & 1, wn = wid >> 1;           // 2x2 wave grid
    const int MT = 4;                           // 64 rows per wave
    const int NT = BN / 32;                     // 16-col tiles per wave (BN/2 cols)
    int lrow = lane & 15, kg = lane >> 4;

    f32x4 acc[MT][NT];
    #pragma unroll
    for (int i = 0; i < MT; ++i)
        #pragma unroll
        for (int j = 0; j < NT; ++j) acc[i][j] = (f32x4){0.f, 0.f, 0.f, 0.f};

    int ar = tid >> 1;                 // A stage: row handled by this thread
    int akh = (tid & 1) * 16;          // k sub-range base (16 wide)
    int agrow = row0 + ar;

    for (int k0 = 0; k0 < K; k0 += BK) {
        // ---- stage A (128 x 32) ----
        unsigned short av[16];
        if (A_BF16) {
            const unsigned short* Ab = (const unsigned short*)Av;
            if (agrow < M) {
                const bf16x8* p = (const bf16x8*)&Ab[(size_t)agrow * K + k0 + akh];
                bf16x8 v0 = p[0], v1 = p[1];
                #pragma unroll
                for (int j = 0; j < 8; ++j) { av[j] = (unsigned short)v0[j]; av[8 + j] = (unsigned short)v1[j]; }
            } else {
                #pragma unroll
                for (int j = 0; j < 16; ++j) av[j] = 0;
            }
        } else {
            const float* Af = (const float*)Av;
            if (agrow < M) {
                const float4* p = (const float4*)&Af[(size_t)agrow * K + k0 + akh];
                #pragma unroll
                for (int q = 0; q < 4; ++q) {
                    float4 v = p[q];
                    av[q * 4 + 0] = f2bf(v.x); av[q * 4 + 1] = f2bf(v.y);
                    av[q * 4 + 2] = f2bf(v.z); av[q * 4 + 3] = f2bf(v.w);
                }
            } else {
                #pragma unroll
                for (int j = 0; j < 16; ++j) av[j] = 0;
            }
        }
        #pragma unroll
        for (int h2 = 0; h2 < 2; ++h2)
            *(bf16x8*)&Asl[(akh >> 3) + h2][ar][0] = *(bf16x8*)&av[h2 * 8];

        // ---- stage B (BN x 32) from BT ----
        for (int idx = tid; idx < BN * 2; idx += 256) {
            int n = idx >> 1, kh = (idx & 1) * 16;
            const bf16x8* p = (const bf16x8*)&BT[(size_t)(n0 + n) * K + k0 + kh];
            bf16x8 v0 = p[0], v1 = p[1];
            *(bf16x8*)&Bsl[(kh >> 3) + 0][n][0] = v0;
            *(bf16x8*)&Bsl[(kh >> 3) + 1][n][0] = v1;
        }
        __syncthreads();

        // ---- fragments + MFMA ----
        bf16x8 af[MT], bfr[NT];
        #pragma unroll
        for (int i = 0; i < MT; ++i)
            af[i] = *(bf16x8*)&Asl[kg][wm * 64 + i * 16 + lrow][0];
        #pragma unroll
        for (int j = 0; j < NT; ++j)
            bfr[j] = *(bf16x8*)&Bsl[kg][wn * (BN / 2) + j * 16 + lrow][0];
        #pragma unroll
        for (int i = 0; i < MT; ++i)
            #pragma unroll
            for (int j = 0; j < NT; ++j)
                acc[i][j] = __builtin_amdgcn_mfma_f32_16x16x32_bf16(af[i], bfr[j], acc[i][j], 0, 0, 0);
        __syncthreads();
    }

    // ---- epilogue: C/D layout col=lane&15, row=(lane>>4)*4+reg ----
    #pragma unroll
    for (int i = 0; i < MT; ++i) {
        #pragma unroll
        for (int j = 0; j < NT; ++j) {
            int col = n0 + wn * (BN / 2) + j * 16 + lrow;
            float bv = bias[col];
            #pragma unroll
            for (int r = 0; r < 4; ++r) {
                int grow = row0 + wm * 64 + i * 16 + kg * 4 + r;
                if (grow < M) {
                    float v = acc[i][j][r] + bv;
                    if (RELU) v = fmaxf(v, 0.0f);
                    if (OUT_BF16) ((unsigned short*)Cout)[(size_t)grow * Nn + col] = f2bf(v);
                    else          ((float*)Cout)[(size_t)grow * Nn + col] = v;
                }
            }
        }
    }
}

// ---------------- propagation: 8 lanes per node, 8 nodes per wave ----------------
// Lane holds 8 classes as 4 packed bf16 pairs (u32x4 = 16B gathers).
// 8-deep chunks + software-pipelined CSR loads -> 64 rows in flight per wave.
template<bool LAST>
__global__ __launch_bounds__(256) void prop8_k(const unsigned short* __restrict__ z,
                                               const unsigned short* __restrict__ z0,
                                               const int* __restrict__ rowstart,
                                               const int2* __restrict__ csr,
                                               const float* __restrict__ dinv,
                                               unsigned short* __restrict__ znew,
                                               float* __restrict__ out, int N_) {
    int node = blockIdx.x * 32 + (threadIdx.x >> 3);
    int l = threadIdx.x & 7;
    if (node >= N_) return;
    int s = rowstart[node], e = rowstart[node + 1];
    float d = dinv[node];
    size_t ro = (size_t)node * 64 + l * 8;
    u32x4 zs = *(const u32x4*)&z[ro];
    float dd = d * d;
    float a[8];
    a[0] = dd * bflo(zs.x); a[1] = dd * bfhi(zs.x);
    a[2] = dd * bflo(zs.y); a[3] = dd * bfhi(zs.y);
    a[4] = dd * bflo(zs.z); a[5] = dd * bfhi(zs.z);
    a[6] = dd * bflo(zs.w); a[7] = dd * bfhi(zs.w);

    int nfull = (e - s) >> 3;
    int j = s;
    long long pv[8];
    if (nfull > 0) {
        #pragma unroll
        for (int q = 0; q < 8; ++q) pv[q] = __builtin_nontemporal_load((const long long*)&csr[j + q]);
    }
    for (int ch = 0; ch < nfull; ++ch) {
        j += 8;
        u32x4 g[8];
        #pragma unroll
        for (int q = 0; q < 8; ++q)
            g[q] = *(const u32x4*)&z[(size_t)(int)pv[q] * 64 + l * 8];
        long long pvn[8];
        bool more = (ch + 1 < nfull);
        if (more) {
            #pragma unroll
            for (int q = 0; q < 8; ++q) pvn[q] = __builtin_nontemporal_load((const long long*)&csr[j + q]);
        }
        #pragma unroll
        for (int q = 0; q < 8; ++q) {
            float w = __int_as_float((int)(pv[q] >> 32));
            a[0] += w * bflo(g[q].x); a[1] += w * bfhi(g[q].x);
            a[2] += w * bflo(g[q].y); a[3] += w * bfhi(g[q].y);
            a[4] += w * bflo(g[q].z); a[5] += w * bfhi(g[q].z);
            a[6] += w * bflo(g[q].w); a[7] += w * bfhi(g[q].w);
        }
        if (more) {
            #pragma unroll
            for (int q = 0; q < 8; ++q) pv[q] = pvn[q];
        }
    }
    for (; j < e; ++j) {
        long long p0 = __builtin_nontemporal_load((const long long*)&csr[j]);
        u32x4 g = *(const u32x4*)&z[(size_t)(int)p0 * 64 + l * 8];
        float w = __int_as_float((int)(p0 >> 32));
        a[0] += w * bflo(g.x); a[1] += w * bfhi(g.x);
        a[2] += w * bflo(g.y); a[3] += w * bfhi(g.y);
        a[4] += w * bflo(g.z); a[5] += w * bfhi(g.z);
        a[6] += w * bflo(g.w); a[7] += w * bfhi(g.w);
    }

    u32x4 z0v = *(const u32x4*)&z0[ro];
    float v[8];
    float z0f[8] = { bflo(z0v.x), bfhi(z0v.x), bflo(z0v.y), bfhi(z0v.y),
                     bflo(z0v.z), bfhi(z0v.z), bflo(z0v.w), bfhi(z0v.w) };
    #pragma unroll
    for (int q = 0; q < 8; ++q) v[q] = (1.0f - ALPHA) * a[q] + ALPHA * z0f[q];

    if (!LAST) {
        u32x4 o;
        o.x = pack2(v[0], v[1]); o.y = pack2(v[2], v[3]);
        o.z = pack2(v[4], v[5]); o.w = pack2(v[6], v[7]);
        __builtin_nontemporal_store(o, (u32x4*)&znew[ro]);
    } else {
        float m = v[0];
        #pragma unroll
        for (int q = 1; q < 8; ++q) m = fmaxf(m, v[q]);
        #pragma unroll
        for (int off = 1; off < 8; off <<= 1) m = fmaxf(m, __shfl_xor(m, off, 64));
        float sum = 0.0f;
        #pragma unroll
        for (int q = 0; q < 8; ++q) sum += expf(v[q] - m);
        #pragma unroll
        for (int off = 1; off < 8; off <<= 1) sum += __shfl_xor(sum, off, 64);
        float lg = logf(sum);
        float4 o0 = make_float4(v[0] - m - lg, v[1] - m - lg, v[2] - m - lg, v[3] - m - lg);
        float4 o1 = make_float4(v[4] - m - lg, v[5] - m - lg, v[6] - m - lg, v[7] - m - lg);
        *(float4*)&out[ro] = o0;
        *(float4*)&out[ro + 4] = o1;
    }
}

// ---------------- launcher ----------------

extern "C" void kernel_launch(void* const* d_in, const int* in_sizes, int n_in,
                              void* d_out, int out_size, void* d_ws, size_t ws_size,
                              hipStream_t stream) {
    const float* x   = (const float*)d_in[0];
    const void*  ei  = d_in[1];
    const float* ew  = (const float*)d_in[2];
    const float* xw  = (const float*)d_in[3];
    const float* W1  = (const float*)d_in[4];
    const float* b1  = (const float*)d_in[5];
    const float* W2  = (const float*)d_in[6];
    const float* b2  = (const float*)d_in[7];

    const int F_ = in_sizes[3];          // 512
    const int N_ = in_sizes[0] / F_;     // 100000
    const int E_ = in_sizes[2];          // 3200000
    const int D_ = in_sizes[5];          // 256
    const int C_ = in_sizes[7];          // 64

    char* base = (char*)d_ws;
    size_t off = 0;
    auto take = [&](size_t bytes) -> void* {
        void* p = base + off;
        off += (bytes + 255) & ~(size_t)255;
        return p;
    };
    int4*  epack    = (int4*) take((size_t)E_ * 16);
    int2*  csr      = (int2*) take((size_t)E_ * 8);
    int*   cntp     = (int*)  take((size_t)NPART * N_ * 4);
    int*   pofs     = (int*)  take((size_t)NPART * N_ * 4);
    int*   cnt      = (int*)  take((size_t)N_ * 4);
    float* dinv     = (float*)take((size_t)N_ * 4);
    int*   rowstart = (int*)  take((size_t)(N_ + 1) * 4);
    int*   flag     = (int*)  take(256);
    int*   bsum     = (int*)  take(4096 * 4);
    int*   boff     = (int*)  take(4096 * 4);
    unsigned short* W1bT = (unsigned short*)take((size_t)F_ * D_ * 2);
    unsigned short* W2bT = (unsigned short*)take((size_t)D_ * C_ * 2);
    unsigned short* h    = (unsigned short*)take((size_t)N_ * D_ * 2);
    unsigned short* z0b  = (unsigned short*)take((size_t)N_ * C_ * 2);
    unsigned short* za   = (unsigned short*)take((size_t)N_ * C_ * 2);
    unsigned short* zb   = (unsigned short*)take((size_t)N_ * C_ * 2);

    (void)ws_size; (void)n_in; (void)out_size;

    int nblk = (N_ + 255) / 256;
    int eblk = (E_ + 255) / 256;

    init_cnt_k<<<(NPART * N_ + 255) / 256, 256, 0, stream>>>(cntp, flag, NPART * N_);
    detect_idx_k<<<1, 256, 0, stream>>>(ei, flag, E_, N_);
    prep_edges_k<<<eblk, 256, 0, stream>>>(ei, ew, epack, cntp, flag, E_, N_);
    combine_k<<<nblk, 256, 0, stream>>>(cntp, pofs, cnt, N_);
    scan1_k<<<nblk, 256, 0, stream>>>(cnt, bsum, N_);
    scan2_k<<<1, 1024, 0, stream>>>(bsum, boff, nblk);
    scan3_k<<<nblk, 256, 0, stream>>>(cnt, boff, rowstart, N_);
    fill_csr_k<<<eblk, 256, 0, stream>>>(epack, pofs, rowstart, csr, E_, N_);
    int gblk8 = (N_ + 7) / 8;
    deg_dinv_k<<<gblk8, 256, 0, stream>>>(csr, rowstart, dinv, N_);
    norm_k<<<gblk8, 256, 0, stream>>>(csr, rowstart, dinv, N_);
    w1t_k<<<(F_ * D_ + 255) / 256, 256, 0, stream>>>(W1, xw, W1bT, F_, D_);
    w2t_k<<<(D_ * C_ + 255) / 256, 256, 0, stream>>>(W2, W2bT, D_, C_);

    int gx = (N_ + 127) / 128;
    // gemm1: h = relu(x @ W1p + b1), output bf16
    mfma_gemm_k<128, false, true, true><<<dim3(gx, D_ / 128), 256, 0, stream>>>(
        (const void*)x, W1bT, b1, (void*)h, N_, F_, D_);
    // gemm2: z0 = h @ W2 + b2, output bf16
    mfma_gemm_k<64, true, false, true><<<dim3(gx, C_ / 64), 256, 0, stream>>>(
        (const void*)h, W2bT, b2, (void*)z0b, N_, D_, C_);

    int pblk = (N_ + 31) / 32;
    const unsigned short* cur = z0b;
    unsigned short* bufs[2] = { za, zb };
    for (int it = 0; it < K_ITERS - 1; ++it) {
        unsigned short* dst = bufs[it & 1];
        prop8_k<false><<<pblk, 256, 0, stream>>>(cur, z0b, rowstart, csr, dinv, dst, nullptr, N_);
        cur = dst;
    }
    prop8_k<true><<<pblk, 256, 0, stream>>>(cur, z0b, rowstart, csr, dinv, nullptr, (float*)d_out, N_);
}